// Round 13
// baseline (354.748 us; speedup 1.0000x reference)
//
#include <hip/hip_runtime.h>
#include <hip/hip_bf16.h>
#include <math.h>

// N_IN=32, N_OUT=31, H=128, npts=65536.
// Per point: X_l (128x32) propagated through Z = W_l @ X, with
// X'[:, :31] = D * Z[:, :31], X'[:, 31] = tanh(Z[:,31] + b).
// MFMA 16x16x32 bf16. Round-8 structure (512 thr, PB=4, ping-pong XT,
// 4 barriers/pass, y prefetch, direct scatter, paired m-tiles in L1/L2:
// wave w=(q=w&3,pg=w>>2) does m-tiles {q,q+4} for pts {2pg,2pg+1} with
// shared B-frags; W3 + b1/b2 in LDS) with occupancy repaired via
// __launch_bounds__(512,4) (unified arch+acc regs capped at 128/wave).
// STRIDE=136 (row payload is 128 ushorts + 8 pad; 120 in r12 aliased rows
// -> correctness failure). LDS = 79,360 B; 2 blocks/CU = 158,720 <= 160K.

using short8 = __attribute__((ext_vector_type(8))) short;
using f32x4  = __attribute__((ext_vector_type(4))) float;

#define PB 4          // points per pass
#define PPB 32        // points per block
#define STRIDE 136    // ushort elems per XT row (272 B: >=128 payload, 16B-aligned)
#define ST3 136       // W3L row stride

__device__ __forceinline__ float fast_tanh(float z) {
    float e = __expf(2.0f * z);
    return 1.0f - 2.0f * __builtin_amdgcn_rcpf(e + 1.0f);
}

// pack 2 f32 -> 1 dword of 2 bf16 (v_cvt_pk_bf16_f32; no builtin on gfx950)
__device__ __forceinline__ unsigned pk2(float lo, float hi) {
    unsigned r;
    asm("v_cvt_pk_bf16_f32 %0, %1, %2" : "=v"(r) : "v"(lo), "v"(hi));
    return r;
}

__device__ __forceinline__ float bf2f(ushort u) {
    union { unsigned u; float f; } c; c.u = ((unsigned)u) << 16; return c.f;
}

__device__ __forceinline__ ushort f2bf1(float f) {
    union { float f; unsigned u; } v; v.f = f;
    unsigned r = v.u + 0x7fffu + ((v.u >> 16) & 1u);
    return (ushort)(r >> 16);
}

__device__ __forceinline__ short8 pack8f(const float* s) {
    union { unsigned u[4]; short8 v; } r;
    #pragma unroll
    for (int qq = 0; qq < 4; ++qq) r.u[qq] = pk2(s[2 * qq], s[2 * qq + 1]);
    return r.v;
}

__device__ __forceinline__ short8 load_row8(const float* p) {
    float tmp[8];
    const float4* p4 = reinterpret_cast<const float4*>(p);
    float4 q0 = p4[0], q1 = p4[1];
    tmp[0]=q0.x; tmp[1]=q0.y; tmp[2]=q0.z; tmp[3]=q0.w;
    tmp[4]=q1.x; tmp[5]=q1.y; tmp[6]=q1.z; tmp[7]=q1.w;
    return pack8f(tmp);
}

__global__ void __launch_bounds__(512, 4)
node_mfma(const float* __restrict__ tptr,
          const float* __restrict__ y,
          const float* __restrict__ W0, const float* __restrict__ b0,
          const float* __restrict__ W1, const float* __restrict__ b1,
          const float* __restrict__ W2, const float* __restrict__ b2,
          const float* __restrict__ W3, const float* __restrict__ b3,
          float* __restrict__ out, float* __restrict__ jac, int npts) {
    // XT[buf][point][col c][row j]; buf0 holds X0/X2, buf1 holds X1
    __shared__ __align__(16) ushort XT[2][PB][32][STRIDE];  // 69,632 B
    __shared__ __align__(16) ushort W3L[32 * ST3];          //  8,704 B
    __shared__ __align__(16) ushort bb12[2][128];           //    512 B
    __shared__ __align__(16) float xb[PB][32];              //    512 B

    const int tid  = threadIdx.x;
    const int w    = tid >> 6;
    const int lane = tid & 63;
    const int r16  = lane & 15;   // A-row / B-col / D-col within tile
    const int g    = lane >> 4;   // k-octet group; D rows = 4g..4g+3
    const int j    = 16 * w + r16;  // L0 row (8 waves cover 128 rows)
    const int q    = w & 3;       // L1/L2 m-tile pair {q, q+4}
    const int pg   = w >> 2;      // L1/L2 point group {2pg, 2pg+1}

    // ---- LDS init: W3 (zero-padded to 32 rows), b1/b2 ----
    {
        int row = tid >> 4, ch = tid & 15;  // 8 elems each
        float tmp[8];
        if (row < 31) {
            const float4* p4 = reinterpret_cast<const float4*>(W3 + row * 128 + ch * 8);
            float4 q0 = p4[0], q1 = p4[1];
            tmp[0]=q0.x; tmp[1]=q0.y; tmp[2]=q0.z; tmp[3]=q0.w;
            tmp[4]=q1.x; tmp[5]=q1.y; tmp[6]=q1.z; tmp[7]=q1.w;
        } else {
            #pragma unroll
            for (int i = 0; i < 8; ++i) tmp[i] = 0.0f;
        }
        *reinterpret_cast<short8*>(&W3L[row * ST3 + ch * 8]) = pack8f(tmp);
    }
    if (tid < 256) {
        int L = tid >> 7, i = tid & 127;
        bb12[L][i] = f2bf1((L ? b2 : b1)[i]);
    }

    // ---- hot weights -> registers ----
    float w0f[8];   // W0[j][g*8+i] f32 (layer-0 dot + X0 build)
    {
        const float4* p4 = reinterpret_cast<const float4*>(W0 + j * 32 + g * 8);
        float4 q0 = p4[0], q1 = p4[1];
        w0f[0]=q0.x; w0f[1]=q0.y; w0f[2]=q0.z; w0f[3]=q0.w;
        w0f[4]=q1.x; w0f[5]=q1.y; w0f[6]=q1.z; w0f[7]=q1.w;
    }
    short8 aW[2][2][4];  // [layer][mt][kc]; lane holds row 16q+64mt+r16
    #pragma unroll
    for (int mt = 0; mt < 2; ++mt) {
        const int row = 16 * q + 64 * mt + r16;
        #pragma unroll
        for (int kc = 0; kc < 4; ++kc) {
            aW[0][mt][kc] = load_row8(W1 + row * 128 + kc * 32 + g * 8);
            aW[1][mt][kc] = load_row8(W2 + row * 128 + kc * 32 + g * 8);
        }
    }
    // layer 3 wave mapping: (m=(w>>1)&1, n=w&1), points (w>>2)+{0,2}
    const int mw = (w >> 1) & 1, nw = w & 1;
    const float b0v = b0[j];
    float b3v[4];
    #pragma unroll
    for (int reg = 0; reg < 4; ++reg) {
        int o = 16 * mw + 4 * g + reg;
        b3v[reg] = (o < 31) ? b3[o] : 0.0f;
    }
    const float force = sinf(tptr[0]);

    // ---- y prefetch for pass 0 ----
    const int pl0 = tid >> 5, c0 = tid & 31;
    const bool act = tid < PB * 32;
    float pf = 0.0f;
    if (act && c0 < 31) pf = y[(size_t)(blockIdx.x * PPB + pl0) * 31 + c0];

    for (int pass = 0; pass < PPB / PB; ++pass) {
        const int pbase = blockIdx.x * PPB + pass * PB;

        // ---- publish x for this pass (from prefetch regs) ----
        if (act) xb[pl0][c0] = (c0 < 31) ? pf : force;
        __syncthreads();  // [E] xb ready; prev-pass XT[0] reads done

        // ---- layer 0: X0 = [D0*W0[:,:31] | h0] -> XT[0] ----
        #pragma unroll
        for (int pl = 0; pl < PB; ++pl) {
            float zp = 0.0f;
            #pragma unroll
            for (int i = 0; i < 8; ++i) zp = fmaf(w0f[i], xb[pl][g * 8 + i], zp);
            zp += __shfl_xor(zp, 16, 64);
            zp += __shfl_xor(zp, 32, 64);
            float h = fast_tanh(zp + b0v);
            float d = 1.0f - h * h;
            #pragma unroll
            for (int i = 0; i < 8; ++i) {
                int c = g * 8 + i;
                XT[0][pl][c][j] = f2bf1((c == 31) ? h : d * w0f[i]);
            }
        }

        // ---- issue y prefetch for next pass (hides under layers 1-3) ----
        if (act && c0 < 31 && pass + 1 < PPB / PB)
            pf = y[(size_t)(pbase + PB + pl0) * 31 + c0];

        __syncthreads();  // [A] X0 ready

        // ---- layers 1, 2: src XT[L] -> dst XT[1-L]; paired m-tiles ----
        #pragma unroll
        for (int L = 0; L < 2; ++L) {
            #pragma unroll
            for (int pi = 0; pi < 2; ++pi) {
                const int pl = 2 * pg + pi;
                f32x4 acc[2][2] = {{{0.f,0.f,0.f,0.f},{0.f,0.f,0.f,0.f}},
                                   {{0.f,0.f,0.f,0.f},{0.f,0.f,0.f,0.f}}};
                __builtin_amdgcn_s_setprio(1);
                #pragma unroll
                for (int kc = 0; kc < 4; ++kc) {
                    short8 bf0 = *reinterpret_cast<const short8*>(&XT[L][pl][r16][kc * 32 + g * 8]);
                    short8 bf1 = *reinterpret_cast<const short8*>(&XT[L][pl][16 + r16][kc * 32 + g * 8]);
                    acc[0][0] = __builtin_amdgcn_mfma_f32_16x16x32_bf16(aW[L][0][kc], bf0, acc[0][0], 0, 0, 0);
                    acc[0][1] = __builtin_amdgcn_mfma_f32_16x16x32_bf16(aW[L][0][kc], bf1, acc[0][1], 0, 0, 0);
                    acc[1][0] = __builtin_amdgcn_mfma_f32_16x16x32_bf16(aW[L][1][kc], bf0, acc[1][0], 0, 0, 0);
                    acc[1][1] = __builtin_amdgcn_mfma_f32_16x16x32_bf16(aW[L][1][kc], bf1, acc[1][1], 0, 0, 0);
                }
                __builtin_amdgcn_s_setprio(0);
                #pragma unroll
                for (int mt = 0; mt < 2; ++mt) {
                    // bias (bf16) from LDS: same addr across r16 -> broadcast
                    uint2 bq = *reinterpret_cast<const uint2*>(&bb12[L][16 * q + 64 * mt + 4 * g]);
                    const ushort* bqs = reinterpret_cast<const ushort*>(&bq);
                    float va[4], vb[4];
                    #pragma unroll
                    for (int reg = 0; reg < 4; ++reg) {
                        float tv = fast_tanh(acc[mt][1][reg] + bf2f(bqs[reg]));
                        float d  = 1.0f - tv * tv;
                        float dd = __shfl(d, lane | 15, 64);
                        va[reg] = dd * acc[mt][0][reg];
                        vb[reg] = (r16 == 15) ? tv : dd * acc[mt][1][reg];
                    }
                    uint2 pa, pb;
                    pa.x = pk2(va[0], va[1]); pa.y = pk2(va[2], va[3]);
                    pb.x = pk2(vb[0], vb[1]); pb.y = pk2(vb[2], vb[3]);
                    const int col = 16 * q + 64 * mt + 4 * g;
                    *reinterpret_cast<uint2*>(&XT[1 - L][pl][r16][col])      = pa;
                    *reinterpret_cast<uint2*>(&XT[1 - L][pl][16 + r16][col]) = pb;
                }
            }
            __syncthreads();  // [B]/[C] X_{L+1} ready
        }

        // ---- layer 3: Y = W3pad @ X2 (X2 in XT[0]); W3 frags from LDS ----
        #pragma unroll
        for (int tsk = 0; tsk < 2; ++tsk) {
            int pl = (w >> 2) + tsk * 2;
            f32x4 a = {0.f, 0.f, 0.f, 0.f};
            __builtin_amdgcn_s_setprio(1);
            #pragma unroll
            for (int kc = 0; kc < 4; ++kc) {
                short8 aw3 = *reinterpret_cast<const short8*>(&W3L[(16 * mw + r16) * ST3 + kc * 32 + g * 8]);
                short8 bf  = *reinterpret_cast<const short8*>(&XT[0][pl][16 * nw + r16][kc * 32 + g * 8]);
                a = __builtin_amdgcn_mfma_f32_16x16x32_bf16(aw3, bf, a, 0, 0, 0);
            }
            __builtin_amdgcn_s_setprio(0);
            size_t p = (size_t)(pbase + pl);
            int c = 16 * nw + r16;
            if ((int)p < npts) {
                #pragma unroll
                for (int reg = 0; reg < 4; ++reg) {
                    int o = 16 * mw + 4 * g + reg;
                    if (o < 31) {
                        if (c == 31) out[p * 31 + o] = a[reg] + b3v[reg];
                        else         jac[(p * 31 + o) * 31 + c] = a[reg];
                    }
                }
            }
        }
        // no barrier here: loop-top [E] separates XT[0] reads from next L0 writes
    }
}

extern "C" void kernel_launch(void* const* d_in, const int* in_sizes, int n_in,
                              void* d_out, int out_size, void* d_ws, size_t ws_size,
                              hipStream_t stream) {
    const float* t  = (const float*)d_in[0];
    const float* y  = (const float*)d_in[1];
    const float* W0 = (const float*)d_in[2];
    const float* b0 = (const float*)d_in[3];
    const float* W1 = (const float*)d_in[4];
    const float* b1 = (const float*)d_in[5];
    const float* W2 = (const float*)d_in[6];
    const float* b2 = (const float*)d_in[7];
    const float* W3 = (const float*)d_in[8];
    const float* b3 = (const float*)d_in[9];

    const int npts = in_sizes[1] / 31;  // 65536
    float* out = (float*)d_out;
    float* jac = out + (size_t)npts * 31;

    const int blocks = (npts + PPB - 1) / PPB;  // 2048
    node_mfma<<<blocks, 512, 0, stream>>>(t, y, W0, b0, W1, b1, W2, b2, W3, b3,
                                          out, jac, npts);
}